// Round 9
// baseline (213.578 us; speedup 1.0000x reference)
//
#include <hip/hip_runtime.h>
#include <hip/hip_bf16.h>

#define LL 4
#define NN 50000
#define DD 64
#define EE 500000
#define HID 256
#define KDIM 512
#define LN_EPS 1e-5f

typedef __bf16 bf16x8 __attribute__((ext_vector_type(8)));
typedef float f32x16 __attribute__((ext_vector_type(16)));

__device__ __forceinline__ void async16(const void* g, void* l) {
    __builtin_amdgcn_global_load_lds(
        (const __attribute__((address_space(1))) void*)g,
        (__attribute__((address_space(3))) void*)l, 16, 0, 0);
}

// ---------- kernel 1: t[l,n,d] = bf16( tanh( imp_l * h[l,n,d] ) ) ----------
__global__ void tanh_conv(const float* __restrict__ h, __bf16* __restrict__ t) {
    int i = (blockIdx.x * 256 + threadIdx.x) * 8;          // 12.8M elems, 8/thread
    int l = i / (NN * DD);
    float imp = (float)(l + 1) * 0.1f;
    const float4* p = (const float4*)(h + i);
    float4 a = p[0];
    float4 b = p[1];
    float x[8] = {a.x, a.y, a.z, a.w, b.x, b.y, b.z, b.w};
    bf16x8 r;
    #pragma unroll
    for (int j = 0; j < 8; ++j) {
        float e2 = __expf(2.0f * (imp * x[j]));
        r[j] = (__bf16)(1.0f - 2.0f / (e2 + 1.0f));
    }
    *(bf16x8*)(t + i) = r;
}

// ---------- kernel 2: W1 (256x512 f32) -> W'' (512 out-cols x 256 K) bf16 ----
// Out-col j<256: Ps row j (src cols of W1); j>=256: Pd row j-256 (dst cols).
// K index k -> feature (l = k>>6, d = k&63) -> W1 col l*128 + 64*(j>=256) + d.
// Chunk layout: w2c[(b*512 + j)*8 + z], b = (k>>4)*2 + ((k>>3)&1), z = k&7.
__global__ void w2_conv(const float* __restrict__ w1, __bf16* __restrict__ o) {
    int t = blockIdx.x * 256 + threadIdx.x;                 // 16384 threads
    int j  = t & 511;
    int b  = t >> 9;              // [0,32)
    int k0 = (b >> 1) * 16 + (b & 1) * 8;
    int r  = j & 255;
    int col = (k0 >> 6) * 128 + ((j >> 8) ? 64 : 0) + (k0 & 63);
    const float4* p = (const float4*)(w1 + r * KDIM + col);
    float4 va = p[0];
    float4 vb = p[1];
    bf16x8 v;
    v[0] = (__bf16)va.x; v[1] = (__bf16)va.y; v[2] = (__bf16)va.z; v[3] = (__bf16)va.w;
    v[4] = (__bf16)vb.x; v[5] = (__bf16)vb.y; v[6] = (__bf16)vb.z; v[7] = (__bf16)vb.w;
    *(bf16x8*)(o + (size_t)t * 8) = v;
}

// ---------- kernel 3: node projections P[n][512] = [Ps|Pd] + 0.5*b1 (bf16) --
// Grid (391, 8). WG = 256 thr / 4 waves; tile = 128 nodes x 64 out-cols.
// B slice (32 KB) staged ONCE via DMA -> zero K-loop barriers; 4 WGs/CU
// (32 KB LDS, bounds(256,4)) doubles resident WGs vs R8 to hide the one-shot
// drain. A loads issued BEFORE the DMA. acc = 2 x f32x16 = 32 regs.
__global__ __launch_bounds__(256, 4)
void node_proj(const __bf16* __restrict__ tb, const __bf16* __restrict__ w2c,
               const float* __restrict__ b1, __bf16* __restrict__ P) {
    __shared__ __align__(16) char smem[32768];
    __bf16* Bs = (__bf16*)smem;       // 16384 bf16 during GEMM
    float*  Cs = (float*)smem;        // 8192 f32 during store bounce

    const int tid  = threadIdx.x;
    const int wave = tid >> 6;
    const int lane = tid & 63;
    const int h32  = lane >> 5;
    const int c32  = lane & 31;
    const int cb   = blockIdx.y;      // which 64 of 512 out-cols
    const int n00  = blockIdx.x * 128;

    // A first: all 16 frags (m = c32 -> node, k = u*16 + h32*8 + z)
    int node = n00 + wave * 32 + c32;
    if (node >= NN) node = NN - 1;
    uint4 a[16];
    #pragma unroll
    for (int u = 0; u < 16; ++u) {
        const __bf16* p = tb + (size_t)(u >> 2) * (NN * DD) + node * DD
                        + (u & 3) * 16 + h32 * 8;
        a[u] = *(const uint4*)p;
    }

    // stage B slice: 32 b-chunks x (64 cols x 8) = 512-elem (1 KB) pieces
    #pragma unroll
    for (int it = 0; it < 8; ++it) {
        int o = it * 2048 + tid * 8;
        async16(w2c + (size_t)(o >> 9) * 4096 + cb * 512 + (o & 511), Bs + o);
    }

    f32x16 acc[2];
    acc[0] = (f32x16)(0.f);
    acc[1] = (f32x16)(0.f);

    __syncthreads();   // B resident

    #pragma unroll
    for (int u = 0; u < 16; ++u) {
        bf16x8 af = __builtin_bit_cast(bf16x8, a[u]);
        const __bf16* Bk = Bs + (u * 2 + h32) * 512 + c32 * 8;
        acc[0] = __builtin_amdgcn_mfma_f32_32x32x16_bf16(
            af, *(const bf16x8*)(Bk), acc[0], 0, 0, 0);
        acc[1] = __builtin_amdgcn_mfma_f32_32x32x16_bf16(
            af, *(const bf16x8*)(Bk + 256), acc[1], 0, 0, 0);
    }
    __syncthreads();   // all waves done reading Bs

    // bounce C through LDS for coalesced bf16 stores
    // C/D 32x32 layout: col = c32, row = (r&3) + 8*(r>>2) + 4*h32
    #pragma unroll
    for (int nt = 0; nt < 2; ++nt) {
        #pragma unroll
        for (int r = 0; r < 16; ++r) {
            int nl = wave * 32 + (r & 3) + 8 * (r >> 2) + 4 * h32;
            Cs[nl * 64 + nt * 32 + c32] = acc[nt][r];
        }
    }
    __syncthreads();
    #pragma unroll
    for (int it = 0; it < 4; ++it) {
        int o   = it * 2048 + tid * 8;
        int nl  = o >> 6;
        int col = o & 63;
        int n   = n00 + nl;
        if (n < NN) {
            int hbase = (cb & 3) * 64 + col;   // h = out-col mod 256
            bf16x8 v;
            #pragma unroll
            for (int z = 0; z < 8; ++z)
                v[z] = (__bf16)(Cs[o + z] + 0.5f * b1[hbase + z]);
            *(bf16x8*)(P + (size_t)n * 512 + cb * 64 + col) = v;
        }
    }
}

// ---------- kernel 4: per-edge gather + LN + ReLU + dot (no MFMA) ----------
// WG = 256 thr = 8 groups of 32 lanes; group handles 16 edges as 4 batches
// of 4, double-buffered: batch b+1's 8 dwordx4 loads are issued before
// computing batch b (~370 cyc) -> L2/L3 gather latency hidden in-wave.
// Lane j covers h = [j*8, j*8+8): group reads each 512 B P-row fully
// coalesced. Regs ~110 -> 4 waves/EU.
#define LOADB(R)                                                              \
    do {                                                                      \
        _Pragma("unroll")                                                     \
        for (int t = 0; t < 4; ++t) {                                         \
            int s = __shfl(sv, lb + eb + t);                                  \
            int d = __shfl(dv, lb + eb + t);                                  \
            R##0[t] = *(const uint4*)(P + ((size_t)s << 9) + (j << 3));       \
            R##1[t] = *(const uint4*)(P + ((size_t)d << 9) + 256 + (j << 3)); \
        }                                                                     \
    } while (0)

#define COMPB(R, B)                                                           \
    do {                                                                      \
        _Pragma("unroll")                                                     \
        for (int t = 0; t < 4; ++t) {                                         \
            bf16x8 A = __builtin_bit_cast(bf16x8, R##0[t]);                   \
            bf16x8 C = __builtin_bit_cast(bf16x8, R##1[t]);                   \
            float x[8];                                                       \
            _Pragma("unroll")                                                 \
            for (int z = 0; z < 8; ++z) x[z] = (float)A[z] + (float)C[z];     \
            float sum = 0.f, sq = 0.f;                                        \
            _Pragma("unroll")                                                 \
            for (int z = 0; z < 8; ++z) {                                     \
                sum += x[z];                                                  \
                sq   = fmaf(x[z], x[z], sq);                                  \
            }                                                                 \
            _Pragma("unroll")                                                 \
            for (int m = 1; m < 32; m <<= 1) {                                \
                sum += __shfl_xor(sum, m);                                    \
                sq  += __shfl_xor(sq,  m);                                    \
            }                                                                 \
            float mu = sum * (1.0f / 256.0f);                                 \
            float rs = rsqrtf(sq * (1.0f / 256.0f) - mu * mu + LN_EPS);       \
            float dot = 0.f;                                                  \
            _Pragma("unroll")                                                 \
            for (int z = 0; z < 8; ++z) {                                     \
                float y = fmaxf(fmaf((x[z] - mu) * rs, gv[z], btv[z]), 0.f);  \
                dot = fmaf(y, wv[z], dot);                                    \
            }                                                                 \
            _Pragma("unroll")                                                 \
            for (int m = 1; m < 32; m <<= 1) dot += __shfl_xor(dot, m);       \
            int e = e0 + (B) * 4 + t;                                         \
            if (j == 0 && e < EE) out[e] = dot + b3v;                         \
        }                                                                     \
    } while (0)

__global__ __launch_bounds__(256, 4)
void edge_out(const __bf16* __restrict__ P, const int* __restrict__ src,
              const int* __restrict__ dst, const float* __restrict__ w3,
              const float* __restrict__ b3, const float* __restrict__ gamma,
              const float* __restrict__ beta, float* __restrict__ out) {
    const int tid = threadIdx.x;
    const int g   = tid >> 5;        // group in WG (0..7)
    const int j   = tid & 31;        // lane in group; h = j*8..+8
    const int lb  = (g & 1) << 5;    // group base within the wave

    // per-lane epilogue constants (24 VGPRs)
    float gv[8], btv[8], wv[8];
    {
        const float4* pg = (const float4*)(gamma + j * 8);
        const float4* pt = (const float4*)(beta + j * 8);
        const float4* pw = (const float4*)(w3 + j * 8);
        #pragma unroll
        for (int z = 0; z < 2; ++z) {
            float4 vg = pg[z], vt = pt[z], vw = pw[z];
            gv [z*4+0] = vg.x; gv [z*4+1] = vg.y; gv [z*4+2] = vg.z; gv [z*4+3] = vg.w;
            btv[z*4+0] = vt.x; btv[z*4+1] = vt.y; btv[z*4+2] = vt.z; btv[z*4+3] = vt.w;
            wv [z*4+0] = vw.x; wv [z*4+1] = vw.y; wv [z*4+2] = vw.z; wv [z*4+3] = vw.w;
        }
    }
    const float b3v = b3[0];
    const int e0 = blockIdx.x * 128 + g * 16;

    // preload this group's 16 edge indices (lanes 0..15 hold them)
    int ej = e0 + (j & 15);
    if (ej >= EE) ej = EE - 1;
    const int sv = src[ej];
    const int dv = dst[ej];

    uint4 ra0[4], ra1[4], rb0[4], rb1[4];
    {
        const int eb = 0;
        LOADB(ra);
    }
    {
        const int eb = 4;
        LOADB(rb);
    }
    {
        const int eb = 8;
        COMPB(ra, 0);
        LOADB(ra);
    }
    {
        const int eb = 12;
        COMPB(rb, 1);
        LOADB(rb);
    }
    COMPB(ra, 2);
    COMPB(rb, 3);
}

extern "C" void kernel_launch(void* const* d_in, const int* in_sizes, int n_in,
                              void* d_out, int out_size, void* d_ws, size_t ws_size,
                              hipStream_t stream) {
    const float* h_all  = (const float*)d_in[0];
    const int*   src    = (const int*)  d_in[1];
    const int*   dst    = (const int*)  d_in[2];
    const float* W1     = (const float*)d_in[3];
    const float* b1     = (const float*)d_in[4];
    const float* W3     = (const float*)d_in[5];
    const float* b3     = (const float*)d_in[6];
    const float* gamma2 = (const float*)d_in[7];
    const float* beta2  = (const float*)d_in[8];
    float* out = (float*)d_out;

    __bf16* tb  = (__bf16*)d_ws;                       // 12.8M bf16 = 25.6 MB
    __bf16* w2c = tb + (size_t)LL * NN * DD;           // 131072 bf16 = 256 KB
    __bf16* P   = w2c + 131072;                        // 50000*512 bf16 = 51.2 MB

    tanh_conv<<<6250, 256, 0, stream>>>(h_all, tb);
    w2_conv<<<64, 256, 0, stream>>>(W1, w2c);
    node_proj<<<dim3((NN + 127) / 128, 8), 256, 0, stream>>>(tb, w2c, b1, P);
    edge_out<<<(EE + 127) / 128, 256, 0, stream>>>(P, src, dst, W3, b3,
                                                   gamma2, beta2, out);
}

// Round 10
// 204.906 us; speedup vs baseline: 1.0423x; 1.0423x over previous
//
#include <hip/hip_runtime.h>
#include <hip/hip_bf16.h>

#define LL 4
#define NN 50000
#define DD 64
#define EE 500000
#define HID 256
#define KDIM 512
#define LN_EPS 1e-5f

typedef __bf16 bf16x8 __attribute__((ext_vector_type(8)));
typedef float f32x16 __attribute__((ext_vector_type(16)));

__device__ __forceinline__ void async16(const void* g, void* l) {
    __builtin_amdgcn_global_load_lds(
        (const __attribute__((address_space(1))) void*)g,
        (__attribute__((address_space(3))) void*)l, 16, 0, 0);
}

// ---------- kernel 1: W1 (256x512 f32) -> W'' (512 out-cols x 256 K) bf16 ----
// Out-col j<256: Ps row j (src cols of W1); j>=256: Pd row j-256 (dst cols).
// K index k -> feature (l = k>>6, d = k&63) -> W1 col l*128 + 64*(j>=256) + d.
// Chunk layout: w2c[(b*512 + j)*8 + z], b = (k>>4)*2 + ((k>>3)&1), z = k&7.
__global__ void w2_conv(const float* __restrict__ w1, __bf16* __restrict__ o) {
    int t = blockIdx.x * 256 + threadIdx.x;                 // 16384 threads
    int j  = t & 511;
    int b  = t >> 9;              // [0,32)
    int k0 = (b >> 1) * 16 + (b & 1) * 8;
    int r  = j & 255;
    int col = (k0 >> 6) * 128 + ((j >> 8) ? 64 : 0) + (k0 & 63);
    const float4* p = (const float4*)(w1 + r * KDIM + col);
    float4 va = p[0];
    float4 vb = p[1];
    bf16x8 v;
    v[0] = (__bf16)va.x; v[1] = (__bf16)va.y; v[2] = (__bf16)va.z; v[3] = (__bf16)va.w;
    v[4] = (__bf16)vb.x; v[5] = (__bf16)vb.y; v[6] = (__bf16)vb.z; v[7] = (__bf16)vb.w;
    *(bf16x8*)(o + (size_t)t * 8) = v;
}

// ---------- kernel 2: FUSED tanh + node projections -------------------------
// P[n][512] = [Ps|Pd](tanh feats) + 0.5*b1. Grid (391, 2); WG = 256 thr.
// Each WG: 128 nodes x 256 out-cols as 2 inner col-blocks of 128.
// A (node features) read ONCE from h_all as f32, tanh'd inline, kept in 64
// bf16-frag VGPRs across both blocks (kills the tanh_conv kernel + tb and
// the y-fold re-reads: A traffic 205->102 MB). B block (64 KB) staged from
// L2-hot w2c via DMA per block; zero barriers inside the MFMA loop.
__global__ __launch_bounds__(256, 2)
void node_proj(const float* __restrict__ h_all, const __bf16* __restrict__ w2c,
               const float* __restrict__ b1, __bf16* __restrict__ P) {
    __shared__ __align__(16) char smem[65536];
    __bf16* Bs = (__bf16*)smem;       // 32768 bf16 during GEMM (64 KB)
    float*  Cs = (float*)smem;        // 128x128 f32 during store bounce (64 KB)

    const int tid  = threadIdx.x;
    const int wave = tid >> 6;
    const int lane = tid & 63;
    const int h32  = lane >> 5;
    const int c32  = lane & 31;
    const int n00  = blockIdx.x * 128;

    int node = n00 + wave * 32 + c32;
    if (node >= NN) node = NN - 1;

    // load h_all rows (f32) + tanh -> 16 bf16x8 A-frags (64 VGPRs)
    // frag u: k = u*16 + h32*8 + z -> layer l = u>>2, d = (u&3)*16 + h32*8 + z
    bf16x8 a[16];
    #pragma unroll
    for (int uh = 0; uh < 2; ++uh) {
        float4 f[16];
        #pragma unroll
        for (int u8 = 0; u8 < 8; ++u8) {
            int u = uh * 8 + u8;
            const float* p = h_all + ((size_t)(u >> 2) * NN + node) * DD
                           + (u & 3) * 16 + h32 * 8;
            f[u8 * 2]     = *(const float4*)p;
            f[u8 * 2 + 1] = *(const float4*)(p + 4);
        }
        #pragma unroll
        for (int u8 = 0; u8 < 8; ++u8) {
            int u = uh * 8 + u8;
            float imp = (float)((u >> 2) + 1) * 0.1f;
            float xs[8] = {f[u8*2].x, f[u8*2].y, f[u8*2].z, f[u8*2].w,
                           f[u8*2+1].x, f[u8*2+1].y, f[u8*2+1].z, f[u8*2+1].w};
            bf16x8 r;
            #pragma unroll
            for (int z = 0; z < 8; ++z) {
                float e2 = __expf(2.0f * (imp * xs[z]));
                r[z] = (__bf16)(1.0f - 2.0f / (e2 + 1.0f));
            }
            a[u] = r;
        }
    }

    #pragma unroll
    for (int cbi = 0; cbi < 2; ++cbi) {
        const int cc = blockIdx.y * 2 + cbi;   // 128-col slice index [0,4)

        // DMA B slice (64 KB = 16 x 4 KB iters); per b-chunk (32 of them),
        // slice cc's 1024 elems live at w2c[b*4096 + cc*1024 ..]
        #pragma unroll
        for (int it = 0; it < 16; ++it) {
            int o = it * 2048 + tid * 8;
            async16(w2c + (size_t)(o >> 10) * 4096 + cc * 1024 + (o & 1023), Bs + o);
        }

        f32x16 acc[4];
        #pragma unroll
        for (int nt = 0; nt < 4; ++nt) acc[nt] = (f32x16)(0.f);

        __syncthreads();   // B resident (also guards Cs reuse from prev block)

        #pragma unroll
        for (int u = 0; u < 16; ++u) {
            const __bf16* Bk = Bs + (u * 2 + h32) * 1024 + c32 * 8;
            #pragma unroll
            for (int nt = 0; nt < 4; ++nt) {
                bf16x8 bf = *(const bf16x8*)(Bk + nt * 256);
                acc[nt] = __builtin_amdgcn_mfma_f32_32x32x16_bf16(a[u], bf, acc[nt], 0, 0, 0);
            }
        }
        __syncthreads();   // all waves done reading Bs

        // bounce C through LDS for coalesced bf16 stores
        // C/D 32x32 layout: col = c32, row = (r&3) + 8*(r>>2) + 4*h32
        #pragma unroll
        for (int nt = 0; nt < 4; ++nt) {
            #pragma unroll
            for (int r = 0; r < 16; ++r) {
                int nl = wave * 32 + (r & 3) + 8 * (r >> 2) + 4 * h32;
                Cs[nl * 128 + nt * 32 + c32] = acc[nt][r];
            }
        }
        __syncthreads();
        #pragma unroll
        for (int it = 0; it < 8; ++it) {
            int o   = it * 2048 + tid * 8;
            int nl  = o >> 7;
            int col = o & 127;
            int n   = n00 + nl;
            if (n < NN) {
                int hb = ((cc & 1) << 7) | col;   // h = out-col mod 256
                bf16x8 v;
                #pragma unroll
                for (int z = 0; z < 8; ++z)
                    v[z] = (__bf16)(Cs[o + z] + 0.5f * b1[hb + z]);
                *(bf16x8*)(P + (size_t)n * 512 + cc * 128 + col) = v;
            }
        }
        __syncthreads();   // Cs reads done before next block's DMA overwrites
    }
}

// ---------- kernel 3: per-edge gather + LN + ReLU + dot (no MFMA) ----------
// R7 structure (best measured: 71.4 us): 16 groups of 16 lanes per WG, 8
// edges per group, 1-deep software pipeline. Lane j covers h = [j*16,+16);
// a group reads each 512 B P-row fully coalesced. b1 pre-folded into P.
__global__ __launch_bounds__(256, 4)
void edge_out(const __bf16* __restrict__ P, const int* __restrict__ src,
              const int* __restrict__ dst, const float* __restrict__ w3,
              const float* __restrict__ b3, const float* __restrict__ gamma,
              const float* __restrict__ beta, float* __restrict__ out) {
    const int tid = threadIdx.x;
    const int g   = tid >> 4;
    const int j   = tid & 15;

    // per-lane epilogue constants for h = j*16 .. +16 (48 VGPRs)
    float gv[16], btv[16], wv[16];
    {
        const float4* pg = (const float4*)(gamma + j * 16);
        const float4* pt = (const float4*)(beta + j * 16);
        const float4* pw = (const float4*)(w3 + j * 16);
        #pragma unroll
        for (int z = 0; z < 4; ++z) {
            float4 vg = pg[z], vt = pt[z], vw = pw[z];
            gv [z*4+0] = vg.x; gv [z*4+1] = vg.y; gv [z*4+2] = vg.z; gv [z*4+3] = vg.w;
            btv[z*4+0] = vt.x; btv[z*4+1] = vt.y; btv[z*4+2] = vt.z; btv[z*4+3] = vt.w;
            wv [z*4+0] = vw.x; wv [z*4+1] = vw.y; wv [z*4+2] = vw.z; wv [z*4+3] = vw.w;
        }
    }
    const float b3v = b3[0];
    const int e0 = blockIdx.x * 128 + g * 8;

    uint4 cs0, cs1, cd0, cd1, ns0, ns1, nd0, nd1;
    {
        int ec = e0 < EE ? e0 : EE - 1;
        int s = src[ec], d = dst[ec];
        const uint4* ps = (const uint4*)(P + ((size_t)s << 9) + (j << 4));
        const uint4* pd = (const uint4*)(P + ((size_t)d << 9) + 256 + (j << 4));
        cs0 = ps[0]; cs1 = ps[1]; cd0 = pd[0]; cd1 = pd[1];
    }
    #pragma unroll
    for (int i = 0; i < 8; ++i) {
        if (i < 7) {
            int e = e0 + i + 1;
            int ec = e < EE ? e : EE - 1;
            int s = src[ec], d = dst[ec];
            const uint4* ps = (const uint4*)(P + ((size_t)s << 9) + (j << 4));
            const uint4* pd = (const uint4*)(P + ((size_t)d << 9) + 256 + (j << 4));
            ns0 = ps[0]; ns1 = ps[1]; nd0 = pd[0]; nd1 = pd[1];
        }
        bf16x8 A0 = __builtin_bit_cast(bf16x8, cs0);
        bf16x8 A1 = __builtin_bit_cast(bf16x8, cs1);
        bf16x8 C0 = __builtin_bit_cast(bf16x8, cd0);
        bf16x8 C1 = __builtin_bit_cast(bf16x8, cd1);
        float x[16];
        #pragma unroll
        for (int z = 0; z < 8; ++z) {
            x[z]     = (float)A0[z] + (float)C0[z];   // b1 pre-folded into P
            x[z + 8] = (float)A1[z] + (float)C1[z];
        }
        float sum = 0.f, sq = 0.f;
        #pragma unroll
        for (int z = 0; z < 16; ++z) {
            sum += x[z];
            sq   = fmaf(x[z], x[z], sq);
        }
        #pragma unroll
        for (int m = 1; m < 16; m <<= 1) {
            sum += __shfl_xor(sum, m);
            sq  += __shfl_xor(sq,  m);
        }
        float mu = sum * (1.0f / 256.0f);
        float rs = rsqrtf(sq * (1.0f / 256.0f) - mu * mu + LN_EPS);
        float dot = 0.f;
        #pragma unroll
        for (int z = 0; z < 16; ++z) {
            float y = fmaxf(fmaf((x[z] - mu) * rs, gv[z], btv[z]), 0.f);
            dot = fmaf(y, wv[z], dot);
        }
        #pragma unroll
        for (int m = 1; m < 16; m <<= 1) dot += __shfl_xor(dot, m);
        int e = e0 + i;
        if (j == 0 && e < EE) out[e] = dot + b3v;
        cs0 = ns0; cs1 = ns1; cd0 = nd0; cd1 = nd1;
    }
}

extern "C" void kernel_launch(void* const* d_in, const int* in_sizes, int n_in,
                              void* d_out, int out_size, void* d_ws, size_t ws_size,
                              hipStream_t stream) {
    const float* h_all  = (const float*)d_in[0];
    const int*   src    = (const int*)  d_in[1];
    const int*   dst    = (const int*)  d_in[2];
    const float* W1     = (const float*)d_in[3];
    const float* b1     = (const float*)d_in[4];
    const float* W3     = (const float*)d_in[5];
    const float* b3     = (const float*)d_in[6];
    const float* gamma2 = (const float*)d_in[7];
    const float* beta2  = (const float*)d_in[8];
    float* out = (float*)d_out;

    __bf16* w2c = (__bf16*)d_ws;                       // 131072 bf16 = 256 KB
    __bf16* P   = w2c + 131072;                        // 50000*512 bf16 = 51.2 MB

    w2_conv<<<64, 256, 0, stream>>>(W1, w2c);
    node_proj<<<dim3((NN + 127) / 128, 2), 256, 0, stream>>>(h_all, w2c, b1, P);
    edge_out<<<(EE + 127) / 128, 256, 0, stream>>>(P, src, dst, W3, b3,
                                                   gamma2, beta2, out);
}